// Round 12
// baseline (2550.557 us; speedup 1.0000x reference)
//
#include <hip/hip_runtime.h>
#include <stdint.h>

// Problem constants (fixed by setup_inputs)
#define Bn 256
#define Hn 768
#define Tn 128
#define KS 24      // Hn/32 ksteps
#define CBn 48     // col-blocks (j-tiles of 16 hidden units x 3 gates)
#define RGn 4      // row-groups of 64 batch rows
#define NTHR 256   // 4 waves; wave w owns m-tile w (16 rows), all gates, full K

typedef __attribute__((ext_vector_type(8))) short short8;   // 8 bf16
typedef __attribute__((ext_vector_type(4))) float floatx4;  // mfma C/D

static __device__ __forceinline__ unsigned short f2bf(float f) {
  unsigned int x = __float_as_uint(f);
  x += 0x7fffu + ((x >> 16) & 1u);
  return (unsigned short)(x >> 16);
}
static __device__ __forceinline__ float bf2f(unsigned short u) {
  return __uint_as_float(((unsigned int)u) << 16);
}

// ---------------------------------------------------------------------------
// Swizzle W_hh (2304x768 fp32 row-major) into slice-contiguous B-fragment
// order, bf16 hi/lo interleaved per chunk. Slice cb (147456 B): chunk
// c = (g*24+ks)*2 + plane, 1 KiB each; within a chunk lane L holds
// W[g*768 + cb*16 + (L&15)][ks*32 + (L>>4)*8 .. +8]. Reads of chunk_base +
// lane*16B are perfectly coalesced 1-KiB wave transactions.
// ---------------------------------------------------------------------------
__global__ void swz_w(const float* __restrict__ W,
                      unsigned short* __restrict__ wsw) {
  int i = blockIdx.x * blockDim.x + threadIdx.x;
  if (i >= 2304 * (Hn / 8)) return;
  int n  = i / (Hn / 8);
  int k0 = (i % (Hn / 8)) * 8;
  int g = n / Hn, jj = n % Hn;
  int cb = jj >> 4, l15 = jj & 15;
  int ks = k0 >> 5, k8 = (k0 >> 3) & 3;
  int lane = l15 + 16 * k8;
  unsigned short* slice = wsw + (size_t)cb * 73728;
  size_t offh = ((size_t)((g * KS + ks) * 2 + 0)) * 512 + (size_t)lane * 8;
  size_t offl = ((size_t)((g * KS + ks) * 2 + 1)) * 512 + (size_t)lane * 8;
  const float* src = W + (size_t)n * Hn + k0;
  short8 h8, l8;
#pragma unroll
  for (int q = 0; q < 8; ++q) {
    float w = src[q];
    unsigned short hb = f2bf(w);
    h8[q] = (short)hb;
    l8[q] = (short)f2bf(w - bf2f(hb));
  }
  *(short8*)(slice + offh) = h8;
  *(short8*)(slice + offl) = l8;
}

// ---------------------------------------------------------------------------
// Init: h0 planes (bf16 hi/lo) from context; zero ddot.
// hbase layout: [hhi0 | hlo0 | hhi1 | hlo1], each Bn*Hn elements.
// ---------------------------------------------------------------------------
__global__ void init_h(const float* __restrict__ ctx,
                       unsigned short* __restrict__ hbase,
                       float* __restrict__ ddot) {
  int i = blockIdx.x * blockDim.x + threadIdx.x;
  if (i < Bn * Hn) {
    float c = ctx[i];
    unsigned short hb = f2bf(c);
    hbase[i] = hb;                            // hhi0
    hbase[Bn * Hn + i] = f2bf(c - bf2f(hb));  // hlo0
  }
  if (i < Tn * Bn) ddot[i] = 0.f;
}

// ---------------------------------------------------------------------------
// ONE GRU step per dispatch — coherence via the dispatch boundary (proven
// R1/R11). NO LDS, NO barriers: B-fragments are read directly from the
// swizzled global W (R1-proven dataflow); the 4 waves of a block read the
// same slice, so L1 serves most repeats and L2/IC the rest — all overlapped
// with MFMA by the compiler's vmcnt scheduling instead of serialized behind
// a staging barrier (R11's cost). Wave w owns m-tile w (16 rows), all 3
// gates, full K, split-bf16 (3 MFMAs/product).
// ---------------------------------------------------------------------------
__global__ __launch_bounds__(NTHR) void gru_step(
    const unsigned short* __restrict__ wsw,
    const unsigned short* __restrict__ hhi_in,
    const unsigned short* __restrict__ hlo_in,
    unsigned short* __restrict__ hhi_out,
    unsigned short* __restrict__ hlo_out,
    const float* __restrict__ bias_ih, const float* __restrict__ bias_hh,
    const float* __restrict__ fc_w, float* __restrict__ ddot_t) {
  const int cb = blockIdx.x;      // 0..47
  const int rg = blockIdx.y;      // 0..3
  const int tid = threadIdx.x;
  const int lane = tid & 63;
  const int wave = tid >> 6;
  const int ln15 = lane & 15, quad = lane >> 4;
  const int j0 = cb * 16;

  // ---- per-lane constants ----
  const int j = j0 + ln15;
  const float bir = bias_ih[j], biz = bias_ih[Hn + j], bin = bias_ih[2 * Hn + j];
  const float bhr = bias_hh[j], bhz = bias_hh[Hn + j], bhn = bias_hh[2 * Hn + j];
  const float fw = fc_w[j];
  const int mrow0 = rg * 64 + wave * 16;  // wave's 16 rows

  // h_old loads (epilogue inputs) issued early; latency hidden by GEMM
  unsigned short hoh[4], hol[4];
#pragma unroll
  for (int i = 0; i < 4; ++i) {
    size_t idx = (size_t)(mrow0 + quad * 4 + i) * Hn + j;
    hoh[i] = hhi_in[idx];
    hol[i] = hlo_in[idx];
  }

  const unsigned short* Ah_base = hhi_in + (size_t)(mrow0 + ln15) * Hn + quad * 8;
  const unsigned short* Al_base = hlo_in + (size_t)(mrow0 + ln15) * Hn + quad * 8;
  const unsigned short* bsl = wsw + (size_t)cb * 73728 + (size_t)lane * 8;

  floatx4 acc[3];
#pragma unroll
  for (int g = 0; g < 3; ++g) acc[g] = (floatx4){0.f, 0.f, 0.f, 0.f};

  // A chunk 0 prefetch; K-loop fully unrolled so the compiler pipelines the
  // global B loads across ksteps (no barriers anywhere).
  short8 Abh[2][4], Abl[2][4];
#pragma unroll
  for (int q = 0; q < 4; ++q) {
    Abh[0][q] = *(const short8*)(Ah_base + q * 32);
    Abl[0][q] = *(const short8*)(Al_base + q * 32);
  }

#pragma unroll
  for (int c = 0; c < 6; ++c) {
    const int cur = c & 1, nxt = cur ^ 1;
    if (c < 5) {
#pragma unroll
      for (int q = 0; q < 4; ++q) {
        Abh[nxt][q] = *(const short8*)(Ah_base + ((c + 1) * 4 + q) * 32);
        Abl[nxt][q] = *(const short8*)(Al_base + ((c + 1) * 4 + q) * 32);
      }
    }
#pragma unroll
    for (int kk = 0; kk < 4; ++kk) {
      const int ks = c * 4 + kk;
#pragma unroll
      for (int g = 0; g < 3; ++g) {
        const size_t cbase = ((size_t)((g * KS + ks) * 2)) * 512;
        short8 Bh = *(const short8*)(bsl + cbase);
        short8 Bl = *(const short8*)(bsl + cbase + 512);
        acc[g] = __builtin_amdgcn_mfma_f32_16x16x32_bf16(Abh[cur][kk], Bh, acc[g], 0, 0, 0);
        acc[g] = __builtin_amdgcn_mfma_f32_16x16x32_bf16(Abl[cur][kk], Bh, acc[g], 0, 0, 0);
        acc[g] = __builtin_amdgcn_mfma_f32_16x16x32_bf16(Abh[cur][kk], Bl, acc[g], 0, 0, 0);
      }
    }
  }

  // ---- epilogue: gates + h_new + fc partial ----
  float fcv[4];
#pragma unroll
  for (int i = 0; i < 4; ++i) {
    const int r = mrow0 + quad * 4 + i;  // C/D layout: row = quad*4 + i
    float gr = bir + bhr + acc[0][i];
    float gz = biz + bhz + acc[1][i];
    float rr = 1.f / (1.f + __expf(-gr));
    float zz = 1.f / (1.f + __expf(-gz));
    float gn = bin + rr * (acc[2][i] + bhn);
    float nn = 1.f - 2.f / (1.f + __expf(2.f * gn));  // tanh
    float hold = bf2f(hoh[i]) + bf2f(hol[i]);
    float hn = (1.f - zz) * nn + zz * hold;
    size_t idx = (size_t)r * Hn + j;
    unsigned short hb = f2bf(hn);
    hhi_out[idx] = hb;                  // normal stores; CP flushes at boundary
    hlo_out[idx] = f2bf(hn - bf2f(hb));
    fcv[i] = hn * fw;
  }
#pragma unroll
  for (int i = 0; i < 4; ++i) {
    fcv[i] += __shfl_xor(fcv[i], 1);
    fcv[i] += __shfl_xor(fcv[i], 2);
    fcv[i] += __shfl_xor(fcv[i], 4);
    fcv[i] += __shfl_xor(fcv[i], 8);
  }
  if (ln15 == 0) {
#pragma unroll
    for (int i = 0; i < 4; ++i)
      atomicAdd(&ddot_t[mrow0 + quad * 4 + i], fcv[i]);
  }
}

// ---------------------------------------------------------------------------
// Post: softplus -> inclusive scan over T -> normalize -> assemble output.
// ---------------------------------------------------------------------------
__global__ void post_k(const float* __restrict__ ddot,
                       const float* __restrict__ fc_b,
                       const int* __restrict__ npred, float* __restrict__ out) {
  const int b = blockIdx.x;
  const int t = threadIdx.x;  // 0..127
  __shared__ float s[Tn];
  float x = ddot[(size_t)t * Bn + b] + fc_b[0];
  float sp = (x > 20.f) ? x : log1pf(__expf(x));
  s[t] = sp;
  __syncthreads();
  for (int off = 1; off < Tn; off <<= 1) {
    float v = s[t];
    float add = (t >= off) ? s[t - off] : 0.f;
    __syncthreads();
    s[t] = v + add;
    __syncthreads();
  }
  const int n = npred[b];
  const float last = s[n - 1] + 1e-6f;
  float body = (t < n) ? (s[t] / last) : 0.f;
  float* ob = out + (size_t)b * (Tn + 2);
  ob[1 + t] = body;
  if (t == 0) { ob[0] = 0.f; ob[Tn + 1] = 0.f; }
  __syncthreads();
  if (t == 0) ob[n + 1] = 1.f;
}

// ---------------------------------------------------------------------------
extern "C" void kernel_launch(void* const* d_in, const int* in_sizes, int n_in,
                              void* d_out, int out_size, void* d_ws, size_t ws_size,
                              hipStream_t stream) {
  const float* context   = (const float*)d_in[0];
  // d_in[1] = weight_ih: unused by the reference computation
  const float* weight_hh = (const float*)d_in[2];
  const float* bias_ih   = (const float*)d_in[3];
  const float* bias_hh   = (const float*)d_in[4];
  const float* fc_w      = (const float*)d_in[5];
  const float* fc_b      = (const float*)d_in[6];
  const int*   npred     = (const int*)d_in[7];
  float* out = (float*)d_out;

  char* ws = (char*)d_ws;
  size_t o = 0;
  unsigned short* hbase = (unsigned short*)(ws + o); o += (size_t)4 * Bn * Hn * 2;
  unsigned short* wsw   = (unsigned short*)(ws + o); o += (size_t)6 * Hn * Hn * 2;
  float* ddot = (float*)(ws + o); o += (size_t)Tn * Bn * 4;
  // ~8.8 MB of d_ws

  const size_t N = (size_t)Bn * Hn;
  unsigned short* HHI[2] = {hbase, hbase + 2 * N};
  unsigned short* HLO[2] = {hbase + N, hbase + 3 * N};

  swz_w<<<dim3((2304 * (Hn / 8) + 255) / 256), dim3(256), 0, stream>>>(weight_hh, wsw);
  init_h<<<dim3((Bn * Hn + 255) / 256), dim3(256), 0, stream>>>(context, hbase, ddot);

  int cur = 0;
  for (int t = 0; t < Tn; ++t) {
    gru_step<<<dim3(CBn, RGn), dim3(NTHR), 0, stream>>>(
        wsw, HHI[cur], HLO[cur], HHI[1 - cur], HLO[1 - cur],
        bias_ih, bias_hh, fc_w, ddot + (size_t)t * Bn);
    cur ^= 1;
  }

  post_k<<<dim3(Bn), dim3(Tn), 0, stream>>>(ddot, fc_b, npred, out);
}